// Round 1
// baseline (186.335 us; speedup 1.0000x reference)
//
#include <hip/hip_runtime.h>

#define C 2
#define H 200
#define W 200
#define NN 200
#define N4 50                   // float4 groups along n
#define G25 25                  // per-thread handles groups g and g+25
#define TOTAL8 (H * W * G25)    // 1,000,000 threads, 8 n's each
#define PLANE (H * W * NN)      // elements per data plane

typedef unsigned char uchar;
typedef unsigned int uint;
typedef float f32x4 __attribute__((ext_vector_type(4)));

// Pre-kernel: per-(coord, n) byte tables.
//   cxb[x*NN + n] : bit0 = cx (0/1), bit1 = (x1 <= x <= x2)
//   cyb[y*NN + n] : bit0 = cy (0/1), bit1 = (y1 <= y <= y2)
// Same float32 expression as the reference (exact pow2 scale, one IEEE div,
// floorf, clamp) -> bit-exact cell indices.
__global__ __launch_bounds__(256) void prep_kernel(
    const float4* __restrict__ rois4, uchar* __restrict__ cxb, uchar* __restrict__ cyb)
{
    const int i = blockIdx.x * 256 + threadIdx.x;
    if (i >= 2 * W * NN) return;
    const bool isY = (i >= W * NN);
    const int j = isY ? i - W * NN : i;
    const int coord = j / NN;
    const int n = j % NN;
    const float4 r = rois4[n];
    const float lo = isY ? r.y : r.x;
    const float hi = isY ? r.w : r.z;
    const float f = (float)coord;
    const bool in = (f >= lo) & (f <= hi);
    const float cw = fmaxf(hi - lo, 1.0f);
    const float t = (2.0f * (f - lo)) / cw;
    const int c = (int)fminf(fmaxf(floorf(t), 0.0f), (float)(C - 1));
    const uchar b = (uchar)((in ? 2 : 0) | c);
    (isY ? cyb : cxb)[j] = b;
}

__device__ __forceinline__ f32x4 gather4(const float* __restrict__ data,
                                         int pbase, uint cxw, uint cyw)
{
    f32x4 v;
#pragma unroll
    for (int k = 0; k < 4; ++k) {
        const uint bx = (cxw >> (8 * k)) & 0xffu;
        const uint by = (cyw >> (8 * k)) & 0xffu;
        float val = 0.0f;
        if ((bx & by & 2u) != 0u) {
            const int cell = (int)(((by & 1u) << 1) | (bx & 1u));
            val = data[cell * PLANE + pbase + k];
        }
        v[k] = val;
    }
    return v;
}

__global__ __launch_bounds__(256) void crop_split_kernel(
    const float* __restrict__ data,
    const uchar* __restrict__ cxb,
    const uchar* __restrict__ cyb,
    f32x4* __restrict__ out)
{
    const int j = blockIdx.x * 256 + threadIdx.x;
    if (j >= TOTAL8) return;

    const int g   = j % G25;       // group index within first half
    const int pix = j / G25;       // y*W + x
    const int x   = pix % W;
    const int y   = pix / W;
    const int nb0 = g * 4;         // n base of first group
    const int nb1 = nb0 + 100;     // n base of second group (g+25)

    // 2x 4-n table words per axis, aligned u32 loads, coalesced per wave.
    const uint cxw0 = *(const uint*)(cxb + x * NN + nb0);
    const uint cxw1 = *(const uint*)(cxb + x * NN + nb1);
    const uint cyw0 = *(const uint*)(cyb + y * NN + nb0);
    const uint cyw1 = *(const uint*)(cyb + y * NN + nb1);

    const int pbase = pix * NN;
    const f32x4 v0 = gather4(data, pbase + nb0, cxw0, cyw0);
    const f32x4 v1 = gather4(data, pbase + nb1, cxw1, cyw1);

    // Both stores are lane-contiguous (g and g+25 blocks), streaming (nt).
    __builtin_nontemporal_store(v0, &out[pix * N4 + g]);
    __builtin_nontemporal_store(v1, &out[pix * N4 + g + G25]);
}

extern "C" void kernel_launch(void* const* d_in, const int* in_sizes, int n_in,
                              void* d_out, int out_size, void* d_ws, size_t ws_size,
                              hipStream_t stream) {
    const float* data  = (const float*)d_in[0];   // (4,200,200,200) f32
    const float4* rois = (const float4*)d_in[1];  // (200,4) f32
    f32x4* out = (f32x4*)d_out;                   // (200,200,200) f32 as float4

    uchar* cxb = (uchar*)d_ws;                    // 40 kB
    uchar* cyb = cxb + (size_t)W * NN;            // 40 kB

    prep_kernel<<<(2 * W * NN + 255) / 256, 256, 0, stream>>>(rois, cxb, cyb);
    crop_split_kernel<<<(TOTAL8 + 255) / 256, 256, 0, stream>>>(data, cxb, cyb, out);
}

// Round 2
// 181.565 us; speedup vs baseline: 1.0263x; 1.0263x over previous
//
#include <hip/hip_runtime.h>

#define C 2
#define H 200
#define W 200
#define NN 200
#define N4 50                   // float4 groups along n
#define TOTAL4 (H * W * N4)     // 2,000,000 float4 outputs
#define PLANE (H * W * NN)      // elements per data plane

typedef unsigned char uchar;
typedef unsigned int uint;
typedef float f32x4 __attribute__((ext_vector_type(4)));

// Pre-kernel: per-(coord, n) byte tables.
//   cxb[x*NN + n] : bit0 = cx (0/1), bit1 = (x1 <= x <= x2)
//   cyb[y*NN + n] : bit0 = cy (0/1), bit1 = (y1 <= y <= y2)
// Same float32 expression as the reference (exact pow2 scale, one IEEE div,
// floorf, clamp) -> bit-exact cell indices.
__global__ __launch_bounds__(256) void prep_kernel(
    const float4* __restrict__ rois4, uchar* __restrict__ cxb, uchar* __restrict__ cyb)
{
    const int i = blockIdx.x * 256 + threadIdx.x;
    if (i >= 2 * W * NN) return;
    const bool isY = (i >= W * NN);
    const int j = isY ? i - W * NN : i;
    const int coord = j / NN;
    const int n = j % NN;
    const float4 r = rois4[n];
    const float lo = isY ? r.y : r.x;
    const float hi = isY ? r.w : r.z;
    const float f = (float)coord;
    const bool in = (f >= lo) & (f <= hi);
    const float cw = fmaxf(hi - lo, 1.0f);
    const float t = (2.0f * (f - lo)) / cw;
    const int c = (int)fminf(fmaxf(floorf(t), 0.0f), (float)(C - 1));
    const uchar b = (uchar)((in ? 2 : 0) | c);
    (isY ? cyb : cxb)[j] = b;
}

// Round-0 proven structure: one float4 (4 n's) per thread, fully dense
// 1024 B-per-wave output stores. Only change: nontemporal store (output is
// pure streaming, never re-read).
__global__ __launch_bounds__(256) void crop_split_kernel(
    const float* __restrict__ data,
    const uchar* __restrict__ cxb,
    const uchar* __restrict__ cyb,
    f32x4* __restrict__ out)
{
    const int j = blockIdx.x * 256 + threadIdx.x;
    if (j >= TOTAL4) return;

    const int n4  = j % N4;        // float4 group along n (consecutive across lanes)
    const int pix = j / N4;        // y*W + x
    const int x   = pix % W;
    const int y   = pix / W;
    const int nb  = n4 * 4;

    // 4 n's worth of table bytes in one aligned u32 load each (coalesced).
    const uint cxw = *(const uint*)(cxb + x * NN + nb);
    const uint cyw = *(const uint*)(cyb + y * NN + nb);

    const int pbase = pix * NN + nb;

    f32x4 v;
#pragma unroll
    for (int k = 0; k < 4; ++k) {
        const uint bx = (cxw >> (8 * k)) & 0xffu;
        const uint by = (cyw >> (8 * k)) & 0xffu;
        float val = 0.0f;
        if ((bx & by & 2u) != 0u) {
            const int cell = (int)(((by & 1u) << 1) | (bx & 1u));
            val = data[cell * PLANE + pbase + k];
        }
        v[k] = val;
    }
    __builtin_nontemporal_store(v, &out[j]);
}

extern "C" void kernel_launch(void* const* d_in, const int* in_sizes, int n_in,
                              void* d_out, int out_size, void* d_ws, size_t ws_size,
                              hipStream_t stream) {
    const float* data  = (const float*)d_in[0];   // (4,200,200,200) f32
    const float4* rois = (const float4*)d_in[1];  // (200,4) f32
    f32x4* out = (f32x4*)d_out;                   // (200,200,200) f32 as float4

    uchar* cxb = (uchar*)d_ws;                    // 40 kB
    uchar* cyb = cxb + (size_t)W * NN;            // 40 kB

    prep_kernel<<<(2 * W * NN + 255) / 256, 256, 0, stream>>>(rois, cxb, cyb);
    crop_split_kernel<<<(TOTAL4 + 255) / 256, 256, 0, stream>>>(data, cxb, cyb, out);
}